// Round 12
// baseline (100.140 us; speedup 1.0000x reference)
//
#include <hip/hip_runtime.h>
#include <math.h>

// PointWarping: B=4, C=3, N=8192 fp32. Exact 3-NN via direct spatial grid.
//
// 3 dispatches: k_zero (counts) -> k_fill (atomic slot + store point into
// fixed-capacity cell array) -> k_query (16 lanes/query scan the 5x5x5 cell
// block directly; butterfly merge; INLINE wave-cooperative brute fallback).
// ws_size = 256 MiB (observed from harness poison fill) -> cells[] = 41 MB ok.
//
// Exactness: cells h=0.22 on [-3.3,3.3]^3 (clamped). Any point >=3 cells away
// in some axis is > 2h=0.44 away, so if the 3rd-best d^2 within the 5x5x5
// block is <= 0.44^2*0.999 the top-3 is exact; else the query is brute-scanned
// against all 8192 points (also for out-of-range queries and any query
// touching an overflowed cell). Keys are exact u64 (d2_bits<<32|idx):
// fp32-exact, (d2,idx)-lex == top_k tie-break, independent of atomic slot
// order (overflowed cells never feed results -> deterministic).

#define BB 4
#define NN 8192
#define NC 30
#define NCELLS (NC * NC * NC)     // 27000
#define NCT (BB * NCELLS)         // 108000
#define CAP 24                    // slots per cell (Poisson(<=5.5) overflow ~0)
#define GRID_R 3.3f
#define GRID_INVH (1.0f / 0.22f)
#define D3_THR (0.44f * 0.44f * 0.999f)

typedef unsigned long long u64;

__device__ __forceinline__ int cell_of(float x) {
  int c = (int)floorf((x + GRID_R) * GRID_INVH);
  return min(max(c, 0), NC - 1);
}

__device__ __forceinline__ void merge3(u64& a0, u64& a1, u64& a2,
                                       u64 b0, u64 b1, u64 b2) {
  const u64 lo0 = a0 < b0 ? a0 : b0;
  const u64 hi0 = a0 < b0 ? b0 : a0;
  const u64 lo1 = a1 < b1 ? a1 : b1;
  const u64 lo2 = a2 < b2 ? a2 : b2;
  const u64 o1 = hi0 < lo1 ? hi0 : lo1;
  const u64 t = hi0 < lo1 ? lo1 : hi0;
  a0 = lo0;
  a1 = o1;
  a2 = t < lo2 ? t : lo2;
}

__device__ __forceinline__ void insert3(u64& s0, u64& s1, u64& s2, u64 key) {
  const bool c0 = key < s0;
  const bool c1 = key < s1;
  const bool c2 = key < s2;
  s2 = c1 ? s1 : (c2 ? key : s2);
  s1 = c0 ? s0 : (c1 ? key : s1);
  s0 = c0 ? key : s0;
}

__device__ __forceinline__ void wave_merge3(u64& s0, u64& s1, u64& s2) {
#pragma unroll
  for (int mask = 32; mask >= 1; mask >>= 1) {
    const u64 b0 = __shfl_xor(s0, mask, 64);
    const u64 b1 = __shfl_xor(s1, mask, 64);
    const u64 b2 = __shfl_xor(s2, mask, 64);
    merge3(s0, s1, s2, b0, b1, b2);
  }
}

__device__ __forceinline__ void cand1(const float4& a, float qx, float qy,
                                      float qz, u64& s0, u64& s1, u64& s2) {
  const float dx = a.x - qx, dy = a.y - qy, dz = a.z - qz;
  const float d2 = fmaf(dx, dx, fmaf(dy, dy, dz * dz));
  insert3(s0, s1, s2,
          ((u64)__float_as_uint(d2) << 32) | (unsigned)__float_as_uint(a.w));
}

// IDW epilogue for one query (indices from low words of s0..s2)
__device__ __forceinline__ void idw_out(int b, int qn, float qx, float qy,
                                        float qz, u64 s0, u64 s1, u64 s2,
                                        const float* __restrict__ P1,
                                        const float* __restrict__ F1,
                                        float* __restrict__ out) {
  const int idxs[3] = {(int)(unsigned)s0 & (NN - 1),
                       (int)(unsigned)s1 & (NN - 1),
                       (int)(unsigned)s2 & (NN - 1)};
  float w[3], gfx[3], gfy[3], gfz[3];
  float wsumv = 0.0f;
#pragma unroll
  for (int r = 0; r < 3; ++r) {
    const int idx = idxs[r];
    const float fx = F1[idx], fy = F1[NN + idx], fz = F1[2 * NN + idx];
    const float kx = P1[idx] + fx;
    const float ky = P1[NN + idx] + fy;
    const float kz = P1[2 * NN + idx] + fz;
    const float dx = kx - qx, dy = ky - qy, dz = kz - qz;
    float d = sqrtf(dx * dx + dy * dy + dz * dz);
    d = fmaxf(d, 1e-10f);
    const float inv = 1.0f / d;
    w[r] = inv; wsumv += inv;
    gfx[r] = fx; gfy[r] = fy; gfz[r] = fz;
  }
  const float invw = 1.0f / wsumv;
  float ox = 0.0f, oy = 0.0f, oz = 0.0f;
#pragma unroll
  for (int r = 0; r < 3; ++r) {
    const float ww = w[r] * invw;
    ox = fmaf(ww, gfx[r], ox);
    oy = fmaf(ww, gfy[r], oy);
    oz = fmaf(ww, gfz[r], oz);
  }
  ox = qx - ox; oy = qy - oy; oz = qz - oz;
  ox = fminf(fmaxf(ox, -10.0f), 10.0f);
  oy = fminf(fmaxf(oy, -10.0f), 10.0f);
  oz = fminf(fmaxf(oz, -10.0f), 10.0f);
  float* o = out + (size_t)b * 3 * NN;
  o[qn] = ox;
  o[NN + qn] = oy;
  o[2 * NN + qn] = oz;
}

__global__ __launch_bounds__(256) void k_zero(int4* __restrict__ p) {
  const int i = blockIdx.x * 256 + threadIdx.x;
  if (i < NCT / 4) p[i] = make_int4(0, 0, 0, 0);
}

__global__ __launch_bounds__(256) void k_fill(const float* __restrict__ p1,
                                              const float* __restrict__ f1,
                                              int* __restrict__ counts,
                                              float4* __restrict__ cells) {
  const int gid = blockIdx.x * 256 + threadIdx.x;  // 0..32767
  const int b = gid >> 13, n = gid & (NN - 1);
  const float* P = p1 + (size_t)b * 3 * NN;
  const float* F = f1 + (size_t)b * 3 * NN;
  const float x = P[n] + F[n];
  const float y = P[NN + n] + F[NN + n];
  const float z = P[2 * NN + n] + F[2 * NN + n];
  const int cid = (cell_of(z) * NC + cell_of(y)) * NC + cell_of(x);
  const int g = b * NCELLS + cid;
  const int slot = atomicAdd(&counts[g], 1);
  if (slot < CAP)
    cells[(size_t)g * CAP + slot] = make_float4(x, y, z, __int_as_float(n));
}

// 16 lanes per query; lane r owns cells r, r+16, ..., of the 125-cell block.
__global__ __launch_bounds__(256) void k_query(const float* __restrict__ p1,
                                               const float* __restrict__ p2,
                                               const float* __restrict__ f1,
                                               const int* __restrict__ counts,
                                               const float4* __restrict__ cells,
                                               float* __restrict__ out) {
  const int tid = threadIdx.x;
  const int wl = tid & 63;                          // wave lane
  const int gtid = blockIdx.x * 256 + tid;          // 0..524287
  const int qid = gtid >> 4;
  const int r = gtid & 15;
  const int b = qid >> 13;
  const int qn = qid & (NN - 1);
  const float* P1 = p1 + (size_t)b * 3 * NN;
  const float* P2 = p2 + (size_t)b * 3 * NN;
  const float* F1 = f1 + (size_t)b * 3 * NN;

  const float qx = P2[qn], qy = P2[NN + qn], qz = P2[2 * NN + qn];
  const bool oor = !(fabsf(qx) < GRID_R && fabsf(qy) < GRID_R && fabsf(qz) < GRID_R);

  u64 s0 = ~0ULL, s1 = ~0ULL, s2 = ~0ULL;
  bool ov = false;

  if (!oor) {
    const int qcx = cell_of(qx), qcy = cell_of(qy), qcz = cell_of(qz);
    const int bB = b * NCELLS;

    int gids[8], cnts[8];
#pragma unroll
    for (int k = 0; k < 8; ++k) {
      const int c = r + 16 * k;
      const int dzi = (c * 41) >> 10;       // c/25 for c<128
      const int rem = c - 25 * dzi;
      const int dyi = (rem * 205) >> 10;    // rem/5
      const int dxi = rem - 5 * dyi;
      const int gz = qcz + dzi - 2, gy = qcy + dyi - 2, gx = qcx + dxi - 2;
      const bool valid = (c < 125) & ((unsigned)gz < NC) & ((unsigned)gy < NC) &
                         ((unsigned)gx < NC);
      gids[k] = bB + (valid ? (gz * NC + gy) * NC + gx : 0);
      int cr = counts[gids[k]];             // unconditional load (cell 0 safe)
      cr = valid ? cr : 0;
      ov |= cr > CAP;
      cnts[k] = min(cr, CAP);
    }

#pragma unroll
    for (int k = 0; k < 8; ++k) {
      const size_t base = (size_t)gids[k] * CAP;
      for (int s = 0; s < cnts[k]; ++s) {
        const float4 pt = cells[base + s];
        cand1(pt, qx, qy, qz, s0, s1, s2);
      }
    }
  }

  // merge the 16 partial triples of this query; OR-reduce overflow flag
#pragma unroll
  for (int mask = 1; mask <= 8; mask <<= 1) {
    const u64 b0 = __shfl_xor(s0, mask, 64);
    const u64 b1 = __shfl_xor(s1, mask, 64);
    const u64 b2 = __shfl_xor(s2, mask, 64);
    merge3(s0, s1, s2, b0, b1, b2);
    ov |= (bool)__shfl_xor((int)ov, mask, 64);
  }

  const float d3 = __uint_as_float((unsigned)(s2 >> 32));
  const bool ok = !oor && !ov && (d3 <= D3_THR);  // NaN-safe

  if (r == 0 && ok) idw_out(b, qn, qx, qy, qz, s0, s1, s2, P1, F1, out);

  // inline wave-cooperative brute fallback for this wave's failed queries
  const u64 bal = __ballot(r == 0 && !ok);
  if (bal != 0) {
    const int qid_wb = (blockIdx.x * 256 + (tid & ~63)) >> 4;  // wave's query 0
#pragma unroll
    for (int q = 0; q < 4; ++q) {
      if (!((bal >> (16 * q)) & 1ULL)) continue;
      const float fqx = __shfl(qx, 16 * q, 64);
      const float fqy = __shfl(qy, 16 * q, 64);
      const float fqz = __shfl(qz, 16 * q, 64);
      u64 a0 = ~0ULL, a1 = ~0ULL, a2 = ~0ULL;
      for (int t = 0; t < NN / 64; ++t) {
        const int g = t * 64 + wl;
        const float x = P1[g] + F1[g];
        const float y = P1[NN + g] + F1[NN + g];
        const float z = P1[2 * NN + g] + F1[2 * NN + g];
        const float dx = x - fqx, dy = y - fqy, dz = z - fqz;
        const float d2 = fmaf(dx, dx, fmaf(dy, dy, dz * dz));
        insert3(a0, a1, a2, ((u64)__float_as_uint(d2) << 32) | (unsigned)g);
      }
      wave_merge3(a0, a1, a2);
      if (wl == 0) {
        const int fq = qid_wb + q;
        idw_out(b, fq & (NN - 1), fqx, fqy, fqz, a0, a1, a2, P1, F1, out);
      }
    }
  }
}

extern "C" void kernel_launch(void* const* d_in, const int* in_sizes, int n_in,
                              void* d_out, int out_size, void* d_ws, size_t ws_size,
                              hipStream_t stream) {
  const float* pos1 = (const float*)d_in[0];
  const float* pos2 = (const float*)d_in[1];
  const float* flow1 = (const float*)d_in[2];
  float* out = (float*)d_out;

  // ws layout: counts (432000 B, 16B-aligned size) then cells (41.5 MB)
  char* ws = (char*)d_ws;
  int* counts = (int*)ws;                        // NCT ints
  float4* cells = (float4*)(ws + (size_t)NCT * 4);  // NCT*CAP float4

  k_zero<<<dim3((NCT / 4 + 255) / 256), dim3(256), 0, stream>>>((int4*)counts);
  k_fill<<<dim3(BB * NN / 256), dim3(256), 0, stream>>>(pos1, flow1, counts, cells);
  k_query<<<dim3(BB * NN * 16 / 256), dim3(256), 0, stream>>>(pos1, pos2, flow1,
                                                              counts, cells, out);
}